// Round 20
// baseline (243.091 us; speedup 1.0000x reference)
//
#include <hip/hip_runtime.h>

// LIIF local-ensemble upsampling — bf16 MFMA, transposed GEMM (r19 base).
// WG = 256 threads (4 waves) = 16 queries x 4 corners = M=64 rows.
// r20 change: barrier-shadow K-chunks — wave wv writes h-cols [wv*64,+64)
// for ALL rows, and layer-2/3 K-steps ks in {2wv,2wv+1} read exactly those
// bytes (same-wave LDS RAW, lgkmcnt-ordered, no barrier needed). Each layer
// runs its own 2 K-steps BEFORE the barrier: store h -> own(2ks) -> sync ->
// rest(6ks). 25% of each K-loop executes in the barrier shadow. Register-
// neutral; 3 barriers unchanged.
// Canaries: WRITE_SIZE ~66MB, absmax 3.9e-3, arch VGPR <= 64.

typedef __bf16 bf16x8 __attribute__((ext_vector_type(8)));
typedef float  f32x4  __attribute__((ext_vector_type(4)));
typedef unsigned int u32x2 __attribute__((ext_vector_type(2)));

#define LDS_SWZ(row, kbyte) ((kbyte) ^ (((row) & 7) << 4))

// ws layout: bf16 weight fragments (ushort units), then x_t at byte 1MB
#define WP1_U 0
#define WP2_U (48 * 512)
#define WP3_U (176 * 512)
#define XT_OFF (1 << 20)

// ---------------- merged prep: weights -> bf16 fragments; x -> channel-last bf16 ----------------
__global__ __launch_bounds__(256) void prep_all(
    const float* __restrict__ W1, const float* __restrict__ W2,
    const float* __restrict__ W3, const float* __restrict__ x,
    ushort* __restrict__ ws, char* __restrict__ xt)
{
    const int blk = blockIdx.x;
    if (blk < 208) {
        const int l = threadIdx.x;
        if (l >= 64) return;
        const float* W; int Kreal, N, ks, nt; size_t off;
        if (blk < 48)       { W = W1; Kreal = 66;  N = 256; ks = blk >> 4;  nt = blk & 15; off = WP1_U + (size_t)blk * 512; }
        else if (blk < 176) { int b2 = blk - 48;  W = W2; Kreal = 256; N = 256; ks = b2 >> 4; nt = b2 & 15; off = WP2_U + (size_t)b2 * 512; }
        else                { int b3 = blk - 176; W = W3; Kreal = 256; N = 64;  ks = b3 >> 2; nt = b3 & 3;  off = WP3_U + (size_t)b3 * 512; }

        const int n = nt * 16 + (l & 15);
        ushort v[8];
        #pragma unroll
        for (int j = 0; j < 8; ++j) {
            const int k = ks * 32 + ((l >> 4) * 8) + j;
            const float f = (k < Kreal) ? W[(size_t)k * N + n] : 0.0f;
            v[j] = __builtin_bit_cast(ushort, (__bf16)f);
        }
        *(uint4*)(ws + off + (size_t)l * 8) = *(const uint4*)v;
    } else {
        const int xb = blk - 208;            // b*64 + iy
        const int b = xb >> 6, iy = xb & 63;
        const int ix = threadIdx.x & 63, cq = threadIdx.x >> 6;   // cq: 16-channel group
        ushort v[16];
        #pragma unroll
        for (int j = 0; j < 16; ++j) {
            const int ch = cq * 16 + j;
            const float f = x[(((size_t)b * 64 + ch) * 64 + iy) * 64 + ix];   // coalesced over ix
            v[j] = __builtin_bit_cast(ushort, (__bf16)f);
        }
        char* dst = xt + ((size_t)((b * 4096 + iy * 64 + ix)) * 128) + cq * 32;
        *(uint4*)dst        = *(const uint4*)(v);
        *(uint4*)(dst + 16) = *(const uint4*)(v + 8);
    }
}

__device__ inline unsigned pk2(float a, float b) {
    return (unsigned)__builtin_bit_cast(ushort, (__bf16)a)
         | ((unsigned)__builtin_bit_cast(ushort, (__bf16)b) << 16);
}

// ---------------- one K-step of a hidden layer (4 wa, 4 hb, 16 MFMA) ----------------
__device__ inline void layer_ks(const char* __restrict__ src, const ushort* __restrict__ wpl,
                                int ks, int lane, f32x4 (&acc)[4][4])
{
    const int lrow = lane & 15;
    const int lk   = lane >> 4;
    bf16x8 wa[4];
    #pragma unroll
    for (int mt = 0; mt < 4; ++mt)
        wa[mt] = *(const bf16x8*)(wpl + ((size_t)(ks * 16 + mt) << 9));
    #pragma unroll
    for (int nt = 0; nt < 4; ++nt) {
        const int row   = nt * 16 + lrow;
        const int kbyte = ks * 64 + lk * 16;
        const bf16x8 hb = *(const bf16x8*)(src + row * 512 + LDS_SWZ(row, kbyte));
        __builtin_amdgcn_s_setprio(1);
        #pragma unroll
        for (int mt = 0; mt < 4; ++mt)
            acc[mt][nt] = __builtin_amdgcn_mfma_f32_16x16x32_bf16(wa[mt], hb, acc[mt][nt], 0, 0, 0);
        __builtin_amdgcn_s_setprio(0);
    }
}

// ---------------- one K-step of layer 3 (1 wa, 4 hb, 4 MFMA) ----------------
__device__ inline void layer3_ks(const char* __restrict__ src, const ushort* __restrict__ wp3,
                                 int ks, int wv, int lane, f32x4 (&acc3)[4])
{
    const int lrow = lane & 15;
    const int lk   = lane >> 4;
    const bf16x8 wa = *(const bf16x8*)(wp3 + ((size_t)(ks * 4 + wv) << 9));
    #pragma unroll
    for (int mt = 0; mt < 4; ++mt) {
        const int row   = mt * 16 + lrow;
        const int kbyte = ks * 64 + lk * 16;
        const bf16x8 hb = *(const bf16x8*)(src + row * 512 + LDS_SWZ(row, kbyte));
        __builtin_amdgcn_s_setprio(1);
        acc3[mt] = __builtin_amdgcn_mfma_f32_16x16x32_bf16(wa, hb, acc3[mt], 0, 0, 0);
        __builtin_amdgcn_s_setprio(0);
    }
}

// ---------------- epilogue: relu(acc) -> h[m][n] bf16, 8B contiguous per lane ----------------
__device__ inline void store_hidden_T(char* __restrict__ dst, const f32x4 (&acc)[4][4],
                                      int lane, int wtile4)
{
    const int lrow = lane & 15;
    const int lk   = lane >> 4;
    #pragma unroll
    for (int nt = 0; nt < 4; ++nt) {
        const int row = nt * 16 + lrow;                       // m
        #pragma unroll
        for (int mt = 0; mt < 4; ++mt) {
            const int nb = ((wtile4 + mt) * 16 + lk * 4) * 2; // byte of n within row
            u32x2 p;
            p[0] = pk2(fmaxf(acc[mt][nt][0], 0.0f), fmaxf(acc[mt][nt][1], 0.0f));
            p[1] = pk2(fmaxf(acc[mt][nt][2], 0.0f), fmaxf(acc[mt][nt][3], 0.0f));
            *(u32x2*)(dst + row * 512 + LDS_SWZ(row, nb)) = p;
        }
    }
}

// ---------------- main kernel ----------------
__global__ __launch_bounds__(256, 3) void liif_mfma18_kernel(
    const char* __restrict__ xt,
    const float* __restrict__ b1f, const float* __restrict__ b2f, const float* __restrict__ b3f,
    const ushort* __restrict__ ws, float* __restrict__ out)
{
    __shared__ char bufH[32 * 1024];   // h1/h2 [64 m][512B]

    const int tid  = threadIdx.x;
    const int lane = tid & 63;
    const int wv   = tid >> 6;            // 0..3
    const int lrow = lane & 15;
    const int lk   = lane >> 4;
    const int wtile4 = wv * 4;            // wave's n-row-tile base (x16)

    const int bid0 = blockIdx.x;          // 0..16383
    const int b    = (bid0 & 7) >> 1;     // XCD-pair <-> batch (L2 locality for x_t)
    const int qidx = (bid0 >> 3) * 2 + (bid0 & 1);   // 0..4095, bijective
    const int q0   = qidx << 4;           // 16 queries per WG

    // ---- lane-local geometry: q = q0 + lrow, corner = c ----
    int   pix_off[4];
    float rely[4], relx[4], wgt[4];
    {
        const int q  = q0 + lrow;
        const int yq = q >> 8, xq = q & 255;
        const float cy  = -1.0f + (2.0f * yq + 1.0f) / 256.0f;
        const float cx  = -1.0f + (2.0f * xq + 1.0f) / 256.0f;
        const float lim = 1.0f - 1e-6f;
        float area[4];
        #pragma unroll
        for (int c = 0; c < 4; ++c) {
            const float vx = (c & 2) ? 1.0f : -1.0f;
            const float vy = (c & 1) ? 1.0f : -1.0f;
            float sy = cy + vx * (1.0f / 64.0f) + 1e-6f;
            float sx = cx + vy * (1.0f / 64.0f) + 1e-6f;
            sy = fminf(fmaxf(sy, -lim), lim);
            sx = fminf(fmaxf(sx, -lim), lim);
            int iyv = (int)rintf(((sy + 1.0f) * 64.0f - 1.0f) * 0.5f);
            int ixv = (int)rintf(((sx + 1.0f) * 64.0f - 1.0f) * 0.5f);
            iyv = min(max(iyv, 0), 63);
            ixv = min(max(ixv, 0), 63);
            const float fy = -1.0f + (2.0f * iyv + 1.0f) / 64.0f;
            const float fx = -1.0f + (2.0f * ixv + 1.0f) / 64.0f;
            rely[c] = (cy - fy) * 64.0f;
            relx[c] = (cx - fx) * 64.0f;
            pix_off[c] = (b * 4096 + iyv * 64 + ixv) * 128;
            area[c] = fabsf(rely[c] * relx[c]) + 1e-9f;
        }
        const float tot = area[0] + area[1] + area[2] + area[3];
        #pragma unroll
        for (int c = 0; c < 4; ++c) wgt[c] = area[3 - c] / tot;   // 0<->3, 1<->2 swap
    }

    f32x4 acc[4][4];

    // ---- layer 1 (transposed): A = W1^T frags, B = x_t direct global loads ----
    {
        #pragma unroll
        for (int mt = 0; mt < 4; ++mt) {
            const f32x4 bs = *(const f32x4*)(b1f + (wtile4 + mt) * 16 + lk * 4);
            #pragma unroll
            for (int nt = 0; nt < 4; ++nt) acc[mt][nt] = bs;
        }
        const ushort* wpl = ws + WP1_U + ((size_t)wtile4 << 9) + (lane << 3);
        #pragma unroll 1
        for (int ks = 0; ks < 2; ++ks) {
            bf16x8 wa[4];
            #pragma unroll
            for (int mt = 0; mt < 4; ++mt)
                wa[mt] = *(const bf16x8*)(wpl + ((size_t)(ks * 16 + mt) << 9));
            #pragma unroll
            for (int nt = 0; nt < 4; ++nt) {
                const bf16x8 hb = *(const bf16x8*)(xt + pix_off[nt] + ks * 64 + lk * 16);
                __builtin_amdgcn_s_setprio(1);
                #pragma unroll
                for (int mt = 0; mt < 4; ++mt)
                    acc[mt][nt] = __builtin_amdgcn_mfma_f32_16x16x32_bf16(wa[mt], hb, acc[mt][nt], 0, 0, 0);
                __builtin_amdgcn_s_setprio(0);
            }
        }
        // ks = 2: rel channels (k=64 rel_y, k=65 rel_x), built in-register
        {
            bf16x8 wa[4];
            #pragma unroll
            for (int mt = 0; mt < 4; ++mt)
                wa[mt] = *(const bf16x8*)(wpl + ((size_t)(32 + mt) << 9));
            #pragma unroll
            for (int nt = 0; nt < 4; ++nt) {
                bf16x8 hb = (bf16x8){0, 0, 0, 0, 0, 0, 0, 0};
                if (lk == 0) { hb[0] = (__bf16)rely[nt]; hb[1] = (__bf16)relx[nt]; }
                __builtin_amdgcn_s_setprio(1);
                #pragma unroll
                for (int mt = 0; mt < 4; ++mt)
                    acc[mt][nt] = __builtin_amdgcn_mfma_f32_16x16x32_bf16(wa[mt], hb, acc[mt][nt], 0, 0, 0);
                __builtin_amdgcn_s_setprio(0);
            }
        }
    }
    store_hidden_T(bufH, acc, lane, wtile4);    // h1

    // ---- layer 2: init + OWN K-chunk (reads only self-written h1 cols) ----
    {
        f32x4 acc2[4][4];
        #pragma unroll
        for (int mt = 0; mt < 4; ++mt) {
            const f32x4 bs = *(const f32x4*)(b2f + (wtile4 + mt) * 16 + lk * 4);
            #pragma unroll
            for (int nt = 0; nt < 4; ++nt) acc2[mt][nt] = bs;
        }
        const ushort* wpl = ws + WP2_U + ((size_t)wtile4 << 9) + (lane << 3);
        layer_ks(bufH, wpl, 2 * wv,     lane, acc2);
        layer_ks(bufH, wpl, 2 * wv + 1, lane, acc2);
        __syncthreads();              // h1 fully visible; own chunk already done
        #pragma unroll 1
        for (int ks = 0; ks < 8; ++ks) {
            if ((ks >> 1) == wv) continue;   // own chunk done pre-barrier
            layer_ks(bufH, wpl, ks, lane, acc2);
        }
        #pragma unroll
        for (int mt = 0; mt < 4; ++mt)
            #pragma unroll
            for (int nt = 0; nt < 4; ++nt) acc[mt][nt] = acc2[mt][nt];
    }
    __syncthreads();                  // all h1 reads done before h2 overwrite
    store_hidden_T(bufH, acc, lane, wtile4);    // h2

    // ---- layer 3: init + OWN K-chunk, then barrier, then rest ----
    {
        f32x4 acc3[4];
        const f32x4 bs3 = *(const f32x4*)(b3f + wv * 16 + lk * 4);
        #pragma unroll
        for (int mt = 0; mt < 4; ++mt) acc3[mt] = bs3;

        const ushort* wp3 = ws + WP3_U + (lane << 3);
        layer3_ks(bufH, wp3, 2 * wv,     wv, lane, acc3);
        layer3_ks(bufH, wp3, 2 * wv + 1, wv, lane, acc3);
        __syncthreads();              // h2 fully visible; own chunk already done
        #pragma unroll 1
        for (int ks = 0; ks < 8; ++ks) {
            if ((ks >> 1) == wv) continue;
            layer3_ks(bufH, wp3, ks, wv, lane, acc3);
        }
        // acc3[mt] = pred^T[ch = wv*16+lk*4+r][corner = mt][q = lrow]
        f32x4 res = acc3[0] * wgt[0];
        res += acc3[1] * wgt[1];
        res += acc3[2] * wgt[2];
        res += acc3[3] * wgt[3];
        // direct global store: 4-lane (lk) groups form 64B contiguous segments
        *(f32x4*)(out + ((size_t)b * 65536 + q0 + lrow) * 64 + wv * 16 + lk * 4) = res;
    }
}

extern "C" void kernel_launch(void* const* d_in, const int* in_sizes, int n_in,
                              void* d_out, int out_size, void* d_ws, size_t ws_size,
                              hipStream_t stream) {
    const float* x  = (const float*)d_in[0];
    const float* W1 = (const float*)d_in[1];
    const float* b1 = (const float*)d_in[2];
    const float* W2 = (const float*)d_in[3];
    const float* b2 = (const float*)d_in[4];
    const float* W3 = (const float*)d_in[5];
    const float* b3 = (const float*)d_in[6];
    float* out = (float*)d_out;
    ushort* wp = (ushort*)d_ws;
    char* xt   = (char*)d_ws + XT_OFF;

    prep_all<<<464, 256, 0, stream>>>(W1, W2, W3, x, wp, xt);
    liif_mfma18_kernel<<<16384, 256, 0, stream>>>(xt, b1, b2, b3, wp, out);
}

// Round 21
// 221.945 us; speedup vs baseline: 1.0953x; 1.0953x over previous
//
#include <hip/hip_runtime.h>

// LIIF local-ensemble upsampling — bf16 MFMA, transposed GEMM (r19 base).
// WG = 256 threads (4 waves) = 16 queries x 4 corners = M=64 rows.
// r21 change: s_setprio REMOVED from all K-loops. T5 evidence (m190):
// setprio is null-to-negative on barrier-synced lockstep GEMM structures
// (only pays with phase-diverse wave roles) — this kernel is 4-wave
// lockstep. Saves ~160 SALU/wave + frees scheduler across MFMA clusters.
// Otherwise byte-identical to r19 (best: 227.1us total, 245.5/dispatch,
// MfmaUtil 42%). Structure converged: 64 AGPR acc + ~60 arch = 128 regs =
// exactly 4 waves/EU; r11/r13/r14/r15/r16/r18/r20 all measured worse.
// Canaries: WRITE_SIZE ~66MB, absmax 3.9e-3, arch VGPR <= 64.

typedef __bf16 bf16x8 __attribute__((ext_vector_type(8)));
typedef float  f32x4  __attribute__((ext_vector_type(4)));
typedef unsigned int u32x2 __attribute__((ext_vector_type(2)));

#define LDS_SWZ(row, kbyte) ((kbyte) ^ (((row) & 7) << 4))

// ws layout: bf16 weight fragments (ushort units), then x_t at byte 1MB
#define WP1_U 0
#define WP2_U (48 * 512)
#define WP3_U (176 * 512)
#define XT_OFF (1 << 20)

// ---------------- merged prep: weights -> bf16 fragments; x -> channel-last bf16 ----------------
// blocks 0..207: weight frag block (64 lanes active)
//   frag block: [ks][ntile][lane][8]  (lane l: k = ks*32+(l>>4)*8+j, n = nt*16+(l&15))
// blocks 208..463: x transpose f32 [b][c][iy][ix] -> bf16 [b][iy][ix][c]
__global__ __launch_bounds__(256) void prep_all(
    const float* __restrict__ W1, const float* __restrict__ W2,
    const float* __restrict__ W3, const float* __restrict__ x,
    ushort* __restrict__ ws, char* __restrict__ xt)
{
    const int blk = blockIdx.x;
    if (blk < 208) {
        const int l = threadIdx.x;
        if (l >= 64) return;
        const float* W; int Kreal, N, ks, nt; size_t off;
        if (blk < 48)       { W = W1; Kreal = 66;  N = 256; ks = blk >> 4;  nt = blk & 15; off = WP1_U + (size_t)blk * 512; }
        else if (blk < 176) { int b2 = blk - 48;  W = W2; Kreal = 256; N = 256; ks = b2 >> 4; nt = b2 & 15; off = WP2_U + (size_t)b2 * 512; }
        else                { int b3 = blk - 176; W = W3; Kreal = 256; N = 64;  ks = b3 >> 2; nt = b3 & 3;  off = WP3_U + (size_t)b3 * 512; }

        const int n = nt * 16 + (l & 15);
        ushort v[8];
        #pragma unroll
        for (int j = 0; j < 8; ++j) {
            const int k = ks * 32 + ((l >> 4) * 8) + j;
            const float f = (k < Kreal) ? W[(size_t)k * N + n] : 0.0f;
            v[j] = __builtin_bit_cast(ushort, (__bf16)f);
        }
        *(uint4*)(ws + off + (size_t)l * 8) = *(const uint4*)v;
    } else {
        const int xb = blk - 208;            // b*64 + iy
        const int b = xb >> 6, iy = xb & 63;
        const int ix = threadIdx.x & 63, cq = threadIdx.x >> 6;   // cq: 16-channel group
        ushort v[16];
        #pragma unroll
        for (int j = 0; j < 16; ++j) {
            const int ch = cq * 16 + j;
            const float f = x[(((size_t)b * 64 + ch) * 64 + iy) * 64 + ix];   // coalesced over ix
            v[j] = __builtin_bit_cast(ushort, (__bf16)f);
        }
        char* dst = xt + ((size_t)((b * 4096 + iy * 64 + ix)) * 128) + cq * 32;
        *(uint4*)dst        = *(const uint4*)(v);
        *(uint4*)(dst + 16) = *(const uint4*)(v + 8);
    }
}

__device__ inline unsigned pk2(float a, float b) {
    return (unsigned)__builtin_bit_cast(ushort, (__bf16)a)
         | ((unsigned)__builtin_bit_cast(ushort, (__bf16)b) << 16);
}

// ---------------- K-loop (transposed): wa[4] per ks, hb streamed ----------------
template<int KSTEPS>
__device__ inline void compute_layer_T(const char* __restrict__ src,
                                       const ushort* __restrict__ wp,
                                       const float* __restrict__ bias,
                                       int lane, int wtile4, f32x4 (&acc)[4][4])
{
    const int lrow = lane & 15;
    const int lk   = lane >> 4;
    #pragma unroll
    for (int mt = 0; mt < 4; ++mt) {
        const f32x4 bs = *(const f32x4*)(bias + (wtile4 + mt) * 16 + lk * 4);
        #pragma unroll
        for (int nt = 0; nt < 4; ++nt) acc[mt][nt] = bs;
    }
    const ushort* wpl = wp + ((size_t)wtile4 << 9) + (lane << 3);
    #pragma unroll 1
    for (int ks = 0; ks < KSTEPS; ++ks) {
        bf16x8 wa[4];
        #pragma unroll
        for (int mt = 0; mt < 4; ++mt)
            wa[mt] = *(const bf16x8*)(wpl + ((size_t)(ks * 16 + mt) << 9));
        #pragma unroll
        for (int nt = 0; nt < 4; ++nt) {
            const int row   = nt * 16 + lrow;
            const int kbyte = ks * 64 + lk * 16;
            const bf16x8 hb = *(const bf16x8*)(src + row * 512 + LDS_SWZ(row, kbyte));
            #pragma unroll
            for (int mt = 0; mt < 4; ++mt)
                acc[mt][nt] = __builtin_amdgcn_mfma_f32_16x16x32_bf16(wa[mt], hb, acc[mt][nt], 0, 0, 0);
        }
    }
}

// ---------------- epilogue: relu(acc) -> h[m][n] bf16, 8B contiguous per lane ----------------
__device__ inline void store_hidden_T(char* __restrict__ dst, const f32x4 (&acc)[4][4],
                                      int lane, int wtile4)
{
    const int lrow = lane & 15;
    const int lk   = lane >> 4;
    #pragma unroll
    for (int nt = 0; nt < 4; ++nt) {
        const int row = nt * 16 + lrow;                       // m
        #pragma unroll
        for (int mt = 0; mt < 4; ++mt) {
            const int nb = ((wtile4 + mt) * 16 + lk * 4) * 2; // byte of n within row
            u32x2 p;
            p[0] = pk2(fmaxf(acc[mt][nt][0], 0.0f), fmaxf(acc[mt][nt][1], 0.0f));
            p[1] = pk2(fmaxf(acc[mt][nt][2], 0.0f), fmaxf(acc[mt][nt][3], 0.0f));
            *(u32x2*)(dst + row * 512 + LDS_SWZ(row, nb)) = p;
        }
    }
}

// ---------------- main kernel ----------------
__global__ __launch_bounds__(256, 3) void liif_mfma19_kernel(
    const char* __restrict__ xt,
    const float* __restrict__ b1f, const float* __restrict__ b2f, const float* __restrict__ b3f,
    const ushort* __restrict__ ws, float* __restrict__ out)
{
    __shared__ char bufH[32 * 1024];   // h1/h2 [64 m][512B]

    const int tid  = threadIdx.x;
    const int lane = tid & 63;
    const int wv   = tid >> 6;            // 0..3
    const int lrow = lane & 15;
    const int lk   = lane >> 4;
    const int wtile4 = wv * 4;            // wave's n-row-tile base (x16)

    const int bid0 = blockIdx.x;          // 0..16383
    const int b    = (bid0 & 7) >> 1;     // XCD-pair <-> batch (L2 locality for x_t)
    const int qidx = (bid0 >> 3) * 2 + (bid0 & 1);   // 0..4095, bijective
    const int q0   = qidx << 4;           // 16 queries per WG

    // ---- lane-local geometry: q = q0 + lrow, corner = c ----
    int   pix_off[4];
    float rely[4], relx[4], wgt[4];
    {
        const int q  = q0 + lrow;
        const int yq = q >> 8, xq = q & 255;
        const float cy  = -1.0f + (2.0f * yq + 1.0f) / 256.0f;
        const float cx  = -1.0f + (2.0f * xq + 1.0f) / 256.0f;
        const float lim = 1.0f - 1e-6f;
        float area[4];
        #pragma unroll
        for (int c = 0; c < 4; ++c) {
            const float vx = (c & 2) ? 1.0f : -1.0f;
            const float vy = (c & 1) ? 1.0f : -1.0f;
            float sy = cy + vx * (1.0f / 64.0f) + 1e-6f;
            float sx = cx + vy * (1.0f / 64.0f) + 1e-6f;
            sy = fminf(fmaxf(sy, -lim), lim);
            sx = fminf(fmaxf(sx, -lim), lim);
            int iyv = (int)rintf(((sy + 1.0f) * 64.0f - 1.0f) * 0.5f);
            int ixv = (int)rintf(((sx + 1.0f) * 64.0f - 1.0f) * 0.5f);
            iyv = min(max(iyv, 0), 63);
            ixv = min(max(ixv, 0), 63);
            const float fy = -1.0f + (2.0f * iyv + 1.0f) / 64.0f;
            const float fx = -1.0f + (2.0f * ixv + 1.0f) / 64.0f;
            rely[c] = (cy - fy) * 64.0f;
            relx[c] = (cx - fx) * 64.0f;
            pix_off[c] = (b * 4096 + iyv * 64 + ixv) * 128;
            area[c] = fabsf(rely[c] * relx[c]) + 1e-9f;
        }
        const float tot = area[0] + area[1] + area[2] + area[3];
        #pragma unroll
        for (int c = 0; c < 4; ++c) wgt[c] = area[3 - c] / tot;   // 0<->3, 1<->2 swap
    }

    f32x4 acc[4][4];

    // ---- layer 1 (transposed): A = W1^T frags, B = x_t direct global loads ----
    {
        #pragma unroll
        for (int mt = 0; mt < 4; ++mt) {
            const f32x4 bs = *(const f32x4*)(b1f + (wtile4 + mt) * 16 + lk * 4);
            #pragma unroll
            for (int nt = 0; nt < 4; ++nt) acc[mt][nt] = bs;
        }
        const ushort* wpl = ws + WP1_U + ((size_t)wtile4 << 9) + (lane << 3);
        #pragma unroll 1
        for (int ks = 0; ks < 2; ++ks) {
            bf16x8 wa[4];
            #pragma unroll
            for (int mt = 0; mt < 4; ++mt)
                wa[mt] = *(const bf16x8*)(wpl + ((size_t)(ks * 16 + mt) << 9));
            #pragma unroll
            for (int nt = 0; nt < 4; ++nt) {
                const bf16x8 hb = *(const bf16x8*)(xt + pix_off[nt] + ks * 64 + lk * 16);
                #pragma unroll
                for (int mt = 0; mt < 4; ++mt)
                    acc[mt][nt] = __builtin_amdgcn_mfma_f32_16x16x32_bf16(wa[mt], hb, acc[mt][nt], 0, 0, 0);
            }
        }
        // ks = 2: rel channels (k=64 rel_y, k=65 rel_x), built in-register
        {
            bf16x8 wa[4];
            #pragma unroll
            for (int mt = 0; mt < 4; ++mt)
                wa[mt] = *(const bf16x8*)(wpl + ((size_t)(32 + mt) << 9));
            #pragma unroll
            for (int nt = 0; nt < 4; ++nt) {
                bf16x8 hb = (bf16x8){0, 0, 0, 0, 0, 0, 0, 0};
                if (lk == 0) { hb[0] = (__bf16)rely[nt]; hb[1] = (__bf16)relx[nt]; }
                #pragma unroll
                for (int mt = 0; mt < 4; ++mt)
                    acc[mt][nt] = __builtin_amdgcn_mfma_f32_16x16x32_bf16(wa[mt], hb, acc[mt][nt], 0, 0, 0);
            }
        }
    }
    store_hidden_T(bufH, acc, lane, wtile4);    // h1
    __syncthreads();

    // ---- layer 2 (transposed): h1 -> h2 (in place in bufH) ----
    compute_layer_T<8>(bufH, ws + WP2_U, b2f, lane, wtile4, acc);
    __syncthreads();                  // all h1 reads done
    store_hidden_T(bufH, acc, lane, wtile4);    // h2
    __syncthreads();

    // ---- layer 3 (transposed) + fused in-register ensemble + direct store ----
    {
        f32x4 acc3[4];
        const f32x4 bs3 = *(const f32x4*)(b3f + wv * 16 + lk * 4);
        #pragma unroll
        for (int mt = 0; mt < 4; ++mt) acc3[mt] = bs3;

        const ushort* wp3 = ws + WP3_U + (lane << 3);
        #pragma unroll 1
        for (int ks = 0; ks < 8; ++ks) {
            const bf16x8 wa = *(const bf16x8*)(wp3 + ((size_t)(ks * 4 + wv) << 9));
            #pragma unroll
            for (int mt = 0; mt < 4; ++mt) {
                const int row   = mt * 16 + lrow;
                const int kbyte = ks * 64 + lk * 16;
                const bf16x8 hb = *(const bf16x8*)(bufH + row * 512 + LDS_SWZ(row, kbyte));
                acc3[mt] = __builtin_amdgcn_mfma_f32_16x16x32_bf16(wa, hb, acc3[mt], 0, 0, 0);
            }
        }
        // acc3[mt] = pred^T[ch = wv*16+lk*4+r][corner = mt][q = lrow]
        f32x4 res = acc3[0] * wgt[0];
        res += acc3[1] * wgt[1];
        res += acc3[2] * wgt[2];
        res += acc3[3] * wgt[3];
        // direct global store: 4-lane (lk) groups form 64B contiguous segments
        *(f32x4*)(out + ((size_t)b * 65536 + q0 + lrow) * 64 + wv * 16 + lk * 4) = res;
    }
}

extern "C" void kernel_launch(void* const* d_in, const int* in_sizes, int n_in,
                              void* d_out, int out_size, void* d_ws, size_t ws_size,
                              hipStream_t stream) {
    const float* x  = (const float*)d_in[0];
    const float* W1 = (const float*)d_in[1];
    const float* b1 = (const float*)d_in[2];
    const float* W2 = (const float*)d_in[3];
    const float* b2 = (const float*)d_in[4];
    const float* W3 = (const float*)d_in[5];
    const float* b3 = (const float*)d_in[6];
    float* out = (float*)d_out;
    ushort* wp = (ushort*)d_ws;
    char* xt   = (char*)d_ws + XT_OFF;

    prep_all<<<464, 256, 0, stream>>>(W1, W2, W3, x, wp, xt);
    liif_mfma19_kernel<<<16384, 256, 0, stream>>>(xt, b1, b2, b3, wp, out);
}